// Round 3
// baseline (467.227 us; speedup 1.0000x reference)
//
#include <hip/hip_runtime.h>

// x: [B=8,C=16,H=512,W=512] f32; phi: [B=8,2,H,W] f32 (dy,dx); out: [B,C,H,W] f32
// Bilinear pull, wrap boundary.
//
// R1/R2 evidence: scattered global gathers are TCP-bound at ~1 distinct-line-touch
// per cycle per CU (R1: 491K touches vs 463K cycles/CU). Fix: stage x rows into LDS
// with coalesced float4 streams, gather via ds_read_b32 (no TA cost, ~2-way bank
// conflicts ~ free). Block = one (batch, 8-row group); stages 31 rows (+-11 halo,
// covers N(0,3) displacement to 3.7 sigma) x 513 cols (col 512 duplicates col 0 so
// x-wrap needs no test) for one channel at a time. Rare out-of-window rows take a
// global-gather fallback (~1e-4 of pixels). blockIdx%8 = batch -> each XCD owns one
// batch, so the 3.9x halo staging re-reads hit that XCD's private L2; HBM reads x once.

constexpr int B = 8, C = 16, H = 512, W = 512;
constexpr int HW = H * W;
constexpr int RG = 8;                    // output rows per block
constexpr int HALO = 11;                 // staged halo rows each side
constexpr int ROWS = RG + 2 * HALO + 1;  // 31 staged rows
constexpr int STRIDE = 516;              // LDS row stride in words (pad: +4 banks/row, 16B aligned)
constexpr int NT = 256;                  // threads per block
constexpr int PX = RG * W;               // 4096 pixels per block
constexpr int PPT = PX / NT;             // 16 pixels per thread

__global__ __launch_bounds__(256) void pull_wrap_kernel(const float* __restrict__ x,
                                                        const float* __restrict__ phi,
                                                        float* __restrict__ out) {
    __shared__ float tile[(ROWS - 1) * STRIDE + W + 1];  // 30*516 + 513 = 15993 words = 63972 B

    const int t  = threadIdx.x;
    const int b  = blockIdx.x & 7;   // batch == XCD affinity
    const int g  = blockIdx.x >> 3;  // row group 0..63
    const int h0 = g * RG;
    const int base = h0 - HALO;      // first staged (unwrapped) row

    // ---- precompute per-pixel sampling coords (phi read once, coalesced) ----
    const float* __restrict__ phiy = phi + (size_t)b * 2 * HW + (size_t)h0 * W;
    const float* __restrict__ phix = phiy + HW;

    float wxA[PPT], wyA[PPT];
    int   idxA[PPT];
    unsigned fb = 0;  // fallback bitmask
#pragma unroll
    for (int i = 0; i < PPT; ++i) {
        int px  = t + i * NT;
        int row = px >> 9;          // /W
        int col = px & (W - 1);
        float cy = phiy[px] + (float)(h0 + row);
        float cx = phix[px] + (float)col;
        float y0f = floorf(cy);
        float x0f = floorf(cx);
        wyA[i] = cy - y0f;
        wxA[i] = cx - x0f;
        int y0u = (int)y0f;         // unwrapped
        int x0  = ((int)x0f) & (W - 1);
        int r0  = y0u - base;       // staged-row index of top tap
        if (r0 >= 0 && r0 <= ROWS - 2) {
            idxA[i] = r0 * STRIDE + x0;          // LDS word offset of v00
        } else {
            fb |= (1u << i);
            idxA[i] = (y0u & (H - 1)) * W + x0;  // wrapped global plane offset of v00
        }
    }

    const float* __restrict__ xb = x + (size_t)b * C * HW;
    float* __restrict__ outb = out + (size_t)b * C * HW + (size_t)h0 * W;

    for (int c = 0; c < C; ++c) {
        const float* __restrict__ xp = xb + (size_t)c * HW;
        __syncthreads();  // previous channel's gather done before overwrite
        // ---- stage 31 rows x 512 cols, coalesced float4 ----
        for (int i = 0; i < 16; ++i) {
            int j = t + i * NT;
            if (j < ROWS * (W / 4)) {
                int row = j >> 7;        // 128 float4 per row
                int cg  = j & 127;
                int gr  = (base + row) & (H - 1);
                float4 v = *(const float4*)(xp + (size_t)gr * W + (size_t)cg * 4);
                *(float4*)&tile[row * STRIDE + cg * 4] = v;
            }
        }
        if (t < ROWS) {  // col 512 := col 0 (x-wrap needs no per-tap test)
            int gr = (base + t) & (H - 1);
            tile[t * STRIDE + W] = xp[(size_t)gr * W];
        }
        __syncthreads();

        float* __restrict__ outc = outb + (size_t)c * HW;
#pragma unroll
        for (int i = 0; i < PPT; ++i) {
            int px = t + i * NT;
            float wx = wxA[i], wy = wyA[i];
            float v00, v01, v10, v11;
            if (!(fb & (1u << i))) {
                int o = idxA[i];
                v00 = tile[o];
                v01 = tile[o + 1];
                v10 = tile[o + STRIDE];
                v11 = tile[o + STRIDE + 1];
            } else {  // rare: tap rows outside staged window -> global gather
                int o  = idxA[i];
                int y0 = o >> 9;
                int x0 = o & (W - 1);
                int y1 = (y0 + 1) & (H - 1);
                int x1 = (x0 + 1) & (W - 1);
                v00 = xp[y0 * W + x0];
                v01 = xp[y0 * W + x1];
                v10 = xp[y1 * W + x0];
                v11 = xp[y1 * W + x1];
            }
            float top = v00 * (1.0f - wx) + v01 * wx;
            float bot = v10 * (1.0f - wx) + v11 * wx;
            outc[px] = top * (1.0f - wy) + bot * wy;
        }
    }
}

extern "C" void kernel_launch(void* const* d_in, const int* in_sizes, int n_in,
                              void* d_out, int out_size, void* d_ws, size_t ws_size,
                              hipStream_t stream) {
    const float* x   = (const float*)d_in[0];
    const float* phi = (const float*)d_in[1];
    float* out = (float*)d_out;

    dim3 block(NT);
    dim3 grid(B * (H / RG));  // 512 blocks: b = blockIdx%8 (XCD affinity), row group = blockIdx/8
    pull_wrap_kernel<<<grid, block, 0, stream>>>(x, phi, out);
}